// Round 1
// 209.307 us; speedup vs baseline: 1.8062x; 1.8062x over previous
//
#include <hip/hip_runtime.h>
#include <math.h>

#define BATCH 1024
#define TT    128
#define NBI   13
#define HH    128
#define T_INP 64
#define BB    16           // batch elements per block
#define NBLK  (BATCH/BB)   // 64 blocks

typedef _Float16 half8 __attribute__((ext_vector_type(8)));
typedef _Float16 half4 __attribute__((ext_vector_type(4)));
typedef float    f32x4 __attribute__((ext_vector_type(4)));

__device__ __forceinline__ unsigned short f16b(float v) {
    return __builtin_bit_cast(unsigned short, (_Float16)v);
}
__device__ __forceinline__ float rcpf_(float x) { return __builtin_amdgcn_rcpf(x); }
__device__ __forceinline__ float sigmoid_(float v) {
    return rcpf_(1.0f + __expf(-v));
}
__device__ __forceinline__ float tanh_(float v) {
    float e = __expf(2.0f * v);
    return 1.0f - 2.0f * rcpf_(e + 1.0f);
}

// ---- ws layout (bytes) ----
#define WS_WHH   0            // ushort[512*128] teacher W_hh (f16)
#define WS_WHAT  131072       // ushort[512*128] folded Ŵ = W_hh + W_ih@W_out (f16)
#define WS_WIHP  262144       // ushort[512*32]  W_ih padded 13->32 (f16)
#define WS_WOUT  294912       // ushort[16*128]  W_out padded 13->16 rows (f16)
#define WS_BT    299008       // float[512] teacher bias = b_ih+b_hh
#define WS_BA    301056       // float[512] auto bias = b_ih+b_hh + W_ih@b_out

__global__ void fold_kernel(const float* __restrict__ W_ih,
                            const float* __restrict__ W_hh,
                            const float* __restrict__ b_ih,
                            const float* __restrict__ b_hh,
                            const float* __restrict__ W_out,
                            const float* __restrict__ b_out,
                            unsigned char* __restrict__ ws)
{
    const int j = blockIdx.x;   // gate row 0..511
    const int k = threadIdx.x;  // hidden col 0..127
    unsigned short* whh16  = (unsigned short*)(ws + WS_WHH);
    unsigned short* what16 = (unsigned short*)(ws + WS_WHAT);
    unsigned short* wihp16 = (unsigned short*)(ws + WS_WIHP);
    unsigned short* wout16 = (unsigned short*)(ws + WS_WOUT);
    float* bias_t = (float*)(ws + WS_BT);
    float* bias_a = (float*)(ws + WS_BA);

    float whh = W_hh[j * HH + k];
    float acc = whh;
#pragma unroll
    for (int m = 0; m < NBI; ++m)
        acc += W_ih[j * NBI + m] * W_out[m * HH + k];
    whh16[j * HH + k]  = f16b(whh);
    what16[j * HH + k] = f16b(acc);

    if (k < 32) wihp16[j * 32 + k] = (k < NBI) ? f16b(W_ih[j * NBI + k]) : (unsigned short)0;
    if (k == 0) {
        float bt = b_ih[j] + b_hh[j];
        bias_t[j] = bt;
        float ba = bt;
#pragma unroll
        for (int m = 0; m < NBI; ++m) ba += W_ih[j * NBI + m] * b_out[m];
        bias_a[j] = ba;
    }
    if (j < 16) wout16[j * HH + k] = (j < NBI) ? f16b(W_out[j * HH + k]) : (unsigned short)0;
}

#define MFMA16(A, B, C) __builtin_amdgcn_mfma_f32_16x16x32_f16((A), (B), (C), 0, 0, 0)

__global__ __launch_bounds__(512, 2)
void lstm_main(const float* __restrict__ x,
               const float* __restrict__ b_out,
               const unsigned char* __restrict__ ws,
               float* __restrict__ out)
{
    const int j  = threadIdx.x;
    const int w  = j >> 6;        // wave 0..7 : owns h-slice [16w,16w+16)
    const int l  = j & 63;
    const int g  = l >> 4;        // lane group 0..3
    const int cb = l & 15;        // B col (batch) / A row within tile
    const int bbase = blockIdx.x * BB;

    const unsigned short* whh16  = (const unsigned short*)(ws + WS_WHH);
    const unsigned short* what16 = (const unsigned short*)(ws + WS_WHAT);
    const unsigned short* wihp16 = (const unsigned short*)(ws + WS_WIHP);
    const unsigned short* wout16 = (const unsigned short*)(ws + WS_WOUT);
    const float* btfp = (const float*)(ws + WS_BT);
    const float* bafp = (const float*)(ws + WS_BA);

    // LDS: [buf][kchunk][batch] of 8xf16. chunk index varies with batch col
    // across lanes -> 2-way banks (free).
    __shared__ half8 h_s[2][16][16];   // h state, k = 8*kc + i
    __shared__ half8 x_s[2][4][16];    // x_t padded to K=32

    // ---- register-resident A fragments ----
    // gate rows for this wave: row(gate) = 128*gate + 16*w + cb ; k = 32*kk + 8*g + i
    half8 wf[4][4];   // W_hh (teacher) -> folded Ŵ (auto)
    half8 wxf[4];     // W_ih padded, single K=32 step
    half8 wof[4];     // W_out rows (m = cb), used by wave 0
    f32x4 binit[4];   // accumulator init = bias, D-layout rows 4g+r
#pragma unroll
    for (int gate = 0; gate < 4; ++gate) {
        const int row = 128 * gate + 16 * w + cb;
#pragma unroll
        for (int kk = 0; kk < 4; ++kk)
            wf[gate][kk] = *(const half8*)(whh16 + row * HH + 32 * kk + 8 * g);
        wxf[gate] = *(const half8*)(wihp16 + row * 32 + 8 * g);
#pragma unroll
        for (int r = 0; r < 4; ++r)
            binit[gate][r] = btfp[128 * gate + 16 * w + 4 * g + r];
    }
#pragma unroll
    for (int kk = 0; kk < 4; ++kk)
        wof[kk] = *(const half8*)(wout16 + cb * HH + 32 * kk + 8 * g);

    float bo[4];
#pragma unroll
    for (int r = 0; r < 4; ++r) {
        const int m = 4 * g + r;
        bo[r] = (m < NBI) ? b_out[m] : 0.0f;
    }

    // ---- init LDS ----
    if (j < 256) h_s[0][j >> 4][j & 15] = (half8)(_Float16)0.0f;   // h^0 = 0
    if (j < 128) ((half8*)x_s)[j] = (half8)(_Float16)0.0f;          // zero pads
    __syncthreads();

    int sb = 0, sm = 0;
    const float* xb = x;
    float* ob = out;
    if (j < 208) {
        sb = j / NBI; sm = j - NBI * sb;
        xb = x   + (size_t)(bbase + sb) * TT * NBI;
        ob = out + (size_t)(bbase + sb) * TT * NBI;
        float v = xb[sm];                                   // x[b][0][m]
        ((_Float16*)&x_s[0][sm >> 3][sb])[sm & 7] = (_Float16)v;
        ob[sm] = v;                                         // out[:,0,:] = x[:,0,:]
    }
    __syncthreads();

    f32x4 c = {0.f, 0.f, 0.f, 0.f};
    int cur = 0;

    for (int t = 0; t < TT - 1; ++t) {
        if (t == T_INP + 1) {
            // switch to folded weights / auto bias (x never materialized)
#pragma unroll
            for (int gate = 0; gate < 4; ++gate) {
                const int row = 128 * gate + 16 * w + cb;
#pragma unroll
                for (int kk = 0; kk < 4; ++kk)
                    wf[gate][kk] = *(const half8*)(what16 + row * HH + 32 * kk + 8 * g);
#pragma unroll
                for (int r = 0; r < 4; ++r)
                    binit[gate][r] = bafp[128 * gate + 16 * w + 4 * g + r];
            }
        }
        const int nxt = cur ^ 1;

        // early-issue next x stage load (hides under MFMA+U)
        float xv = 0.0f;
        const bool do_stage = (j < 208) && (t + 1 <= T_INP);
        if (do_stage) xv = xb[(t + 1) * NBI + sm];

        // ---- G phase: gates = bias + W·h (+ W_ih·x in teacher phase) ----
        f32x4 acc0 = binit[0], acc1 = binit[1], acc2 = binit[2], acc3 = binit[3];
        if (t <= T_INP) {
            half8 xf = x_s[cur][g][cb];
            acc0 = MFMA16(wxf[0], xf, acc0);
            acc1 = MFMA16(wxf[1], xf, acc1);
            acc2 = MFMA16(wxf[2], xf, acc2);
            acc3 = MFMA16(wxf[3], xf, acc3);
        }
        f32x4 pacc = {0.f, 0.f, 0.f, 0.f};
#pragma unroll
        for (int kk = 0; kk < 4; ++kk) {
            half8 hb = h_s[cur][4 * kk + g][cb];
            acc0 = MFMA16(wf[0][kk], hb, acc0);
            acc1 = MFMA16(wf[1][kk], hb, acc1);
            acc2 = MFMA16(wf[2][kk], hb, acc2);
            acc3 = MFMA16(wf[3][kk], hb, acc3);
            if (w == 0) pacc = MFMA16(wof[kk], hb, pacc);   // out[t] = W_out h^t
        }

        // ---- U phase: fully in-register (D rows 4g+r, col cb) ----
        half4 h4v;
#pragma unroll
        for (int r = 0; r < 4; ++r) {
            float ig = sigmoid_(acc0[r]);
            float fg = sigmoid_(acc1[r]);
            float gg = tanh_(acc2[r]);
            float og = sigmoid_(acc3[r]);
            float cn = fg * c[r] + ig * gg;
            c[r] = cn;
            h4v[r] = (_Float16)(og * tanh_(cn));
        }
        {   // h rows 16w+4g+0..3, col cb -> kc = 2w + (g>>1), half (g&1)
            _Float16* hp = (_Float16*)&h_s[nxt][2 * w + (g >> 1)][cb];
            *(half4*)(hp + 4 * (g & 1)) = h4v;
        }
        if (do_stage)
            ((_Float16*)&x_s[nxt][sm >> 3][sb])[sm & 7] = (_Float16)xv;

        if (w == 0 && t >= 1) {
#pragma unroll
            for (int r = 0; r < 4; ++r) {
                const int m = 4 * g + r;
                if (m < NBI)
                    out[((size_t)(bbase + cb) * TT + t) * NBI + m] = pacc[r] + bo[r];
            }
        }
        __syncthreads();
        cur = nxt;
    }

    // ---- epilogue: out[127] = W_out h^127 + b_out ----
    if (w == 0) {
        f32x4 pacc = {0.f, 0.f, 0.f, 0.f};
#pragma unroll
        for (int kk = 0; kk < 4; ++kk) {
            half8 hb = h_s[cur][4 * kk + g][cb];
            pacc = MFMA16(wof[kk], hb, pacc);
        }
#pragma unroll
        for (int r = 0; r < 4; ++r) {
            const int m = 4 * g + r;
            if (m < NBI)
                out[((size_t)(bbase + cb) * TT + (TT - 1)) * NBI + m] = pacc[r] + bo[r];
        }
    }
}

extern "C" void kernel_launch(void* const* d_in, const int* in_sizes, int n_in,
                              void* d_out, int out_size, void* d_ws, size_t ws_size,
                              hipStream_t stream)
{
    const float* x     = (const float*)d_in[0];
    const float* W_ih  = (const float*)d_in[1];
    const float* W_hh  = (const float*)d_in[2];
    const float* b_ih  = (const float*)d_in[3];
    const float* b_hh  = (const float*)d_in[4];
    const float* W_out = (const float*)d_in[5];
    const float* b_out = (const float*)d_in[6];
    float* out = (float*)d_out;
    unsigned char* ws = (unsigned char*)d_ws;

    fold_kernel<<<512, HH, 0, stream>>>(W_ih, W_hh, b_ih, b_hh, W_out, b_out, ws);
    lstm_main<<<NBLK, 512, 0, stream>>>(x, b_out, ws, out);
}

// Round 2
// 186.415 us; speedup vs baseline: 2.0280x; 1.1228x over previous
//
#include <hip/hip_runtime.h>
#include <math.h>

#define BATCH 1024
#define TT    128
#define NBI   13
#define HH    128
#define T_INP 64
#define BB    16           // batch elements per block
#define NBLK  (BATCH/BB)   // 64 blocks

#define LOG2E 1.4426950408889634f

typedef _Float16 half8 __attribute__((ext_vector_type(8)));
typedef _Float16 half4 __attribute__((ext_vector_type(4)));
typedef float    f32x4 __attribute__((ext_vector_type(4)));

__device__ __forceinline__ unsigned short f16b(float v) {
    return __builtin_bit_cast(unsigned short, (_Float16)v);
}
__device__ __forceinline__ float rcpf_(float x) { return __builtin_amdgcn_rcpf(x); }

#if __has_builtin(__builtin_amdgcn_exp2f)
__device__ __forceinline__ float exp2_(float x) { return __builtin_amdgcn_exp2f(x); }
#else
__device__ __forceinline__ float exp2_(float x) { return __expf(x * 0.6931471805599453f); }
#endif

// light barrier: LDS visibility only — do NOT drain vmcnt (global stores / x
// prefetch loads stay in flight across the step boundary)
__device__ __forceinline__ void barrier_lds() {
    asm volatile("s_waitcnt lgkmcnt(0)" ::: "memory");
    __builtin_amdgcn_sched_barrier(0);
    __builtin_amdgcn_s_barrier();
    __builtin_amdgcn_sched_barrier(0);
}

// ---- ws layout (bytes) ----
// gate rows are pre-scaled: i/f/o rows by -log2e (sigmoid via exp2), g rows by
// +2*log2e (tanh via exp2). Biases carry the same per-row scale.
#define WS_WHH   0            // ushort[512*128] teacher W_hh (f16, scaled)
#define WS_WHAT  131072       // ushort[512*128] folded W^ = W_hh + W_ih@W_out (f16, scaled)
#define WS_WIHP  262144       // ushort[512*32]  W_ih padded 13->32 (f16, scaled)
#define WS_WOUT  294912       // ushort[16*128]  W_out padded 13->16 rows (f16, unscaled)
#define WS_BT    299008       // float[512] teacher bias (scaled)
#define WS_BA    301056       // float[512] auto bias (scaled)

__global__ void fold_kernel(const float* __restrict__ W_ih,
                            const float* __restrict__ W_hh,
                            const float* __restrict__ b_ih,
                            const float* __restrict__ b_hh,
                            const float* __restrict__ W_out,
                            const float* __restrict__ b_out,
                            unsigned char* __restrict__ ws)
{
    const int j = blockIdx.x;   // gate row 0..511
    const int k = threadIdx.x;  // hidden col 0..127
    unsigned short* whh16  = (unsigned short*)(ws + WS_WHH);
    unsigned short* what16 = (unsigned short*)(ws + WS_WHAT);
    unsigned short* wihp16 = (unsigned short*)(ws + WS_WIHP);
    unsigned short* wout16 = (unsigned short*)(ws + WS_WOUT);
    float* bias_t = (float*)(ws + WS_BT);
    float* bias_a = (float*)(ws + WS_BA);

    const int gate = j >> 7;
    const float sc = (gate == 2) ? (2.0f * LOG2E) : (-LOG2E);

    float whh = W_hh[j * HH + k];
    float acc = whh;
#pragma unroll
    for (int m = 0; m < NBI; ++m)
        acc += W_ih[j * NBI + m] * W_out[m * HH + k];
    whh16[j * HH + k]  = f16b(sc * whh);
    what16[j * HH + k] = f16b(sc * acc);

    if (k < 32) wihp16[j * 32 + k] = (k < NBI) ? f16b(sc * W_ih[j * NBI + k]) : (unsigned short)0;
    if (k == 0) {
        float bt = b_ih[j] + b_hh[j];
        bias_t[j] = sc * bt;
        float ba = bt;
#pragma unroll
        for (int m = 0; m < NBI; ++m) ba += W_ih[j * NBI + m] * b_out[m];
        bias_a[j] = sc * ba;
    }
    if (j < 16) wout16[j * HH + k] = (j < NBI) ? f16b(W_out[j * HH + k]) : (unsigned short)0;
}

#define MFMA16(A, B, C) __builtin_amdgcn_mfma_f32_16x16x32_f16((A), (B), (C), 0, 0, 0)

__global__ __launch_bounds__(512, 2)
void lstm_main(const float* __restrict__ x,
               const float* __restrict__ b_out,
               const unsigned char* __restrict__ ws,
               float* __restrict__ out)
{
    const int j  = threadIdx.x;
    const int w  = j >> 6;        // wave 0..7 : owns h-slice [16w,16w+16)
    const int l  = j & 63;
    const int g  = l >> 4;        // lane group 0..3
    const int cb = l & 15;        // B col (batch) / A row within tile
    const int bbase = blockIdx.x * BB;

    const unsigned short* whh16  = (const unsigned short*)(ws + WS_WHH);
    const unsigned short* what16 = (const unsigned short*)(ws + WS_WHAT);
    const unsigned short* wihp16 = (const unsigned short*)(ws + WS_WIHP);
    const unsigned short* wout16 = (const unsigned short*)(ws + WS_WOUT);
    const float* btfp = (const float*)(ws + WS_BT);
    const float* bafp = (const float*)(ws + WS_BA);

    __shared__ half8 h_s[2][16][16];   // h state, k = 8*kc + i
    __shared__ half8 x_s[2][4][16];    // x_t padded to K=32

    // ---- register-resident A fragments ----
    half8 wf[4][4];   // W_hh (teacher) -> folded W^ (auto)
    half8 wxf[4];     // W_ih padded, single K=32 step
    half8 wof[4];     // W_out rows (m = cb), used by proj wave
    f32x4 binit[4];   // accumulator init = bias (scaled), D rows 4g+r
#pragma unroll
    for (int gate = 0; gate < 4; ++gate) {
        const int row = 128 * gate + 16 * w + cb;
#pragma unroll
        for (int kk = 0; kk < 4; ++kk)
            wf[gate][kk] = *(const half8*)(whh16 + row * HH + 32 * kk + 8 * g);
        wxf[gate] = *(const half8*)(wihp16 + row * 32 + 8 * g);
#pragma unroll
        for (int r = 0; r < 4; ++r)
            binit[gate][r] = btfp[128 * gate + 16 * w + 4 * g + r];
    }
    const bool projw = (w == 7);   // waves 0-3 stage x; wave 7 projects
#pragma unroll
    for (int kk = 0; kk < 4; ++kk)
        wof[kk] = *(const half8*)(wout16 + cb * HH + 32 * kk + 8 * g);

    float bo[4];
#pragma unroll
    for (int r = 0; r < 4; ++r) {
        const int m = 4 * g + r;
        bo[r] = (m < NBI) ? b_out[m] : 0.0f;
    }
    // proj store base: out[(bbase+cb)*TT*NBI + t*NBI + (4g+r)]
    float* pob = out + (size_t)(bbase + cb) * TT * NBI + 4 * g;

    // ---- init LDS ----
    if (j < 256) h_s[0][j >> 4][j & 15] = (half8)(_Float16)0.0f;   // h^0 = 0
    if (j < 128) ((half8*)x_s)[j] = (half8)(_Float16)0.0f;          // zero pads (both bufs)
    __syncthreads();

    int sb = 0, sm = 0;
    const float* xb = x;
    const bool do_x = (j < 208);
    float xv_hold = 0.0f, xv_pref = 0.0f;
    if (do_x) {
        sb = j / NBI; sm = j - NBI * sb;
        xb = x + (size_t)(bbase + sb) * TT * NBI + sm;
        float v = xb[0];                                    // x[b][0][m]
        ((_Float16*)&x_s[0][sm >> 3][sb])[sm & 7] = (_Float16)v;
        out[(size_t)(bbase + sb) * TT * NBI + sm] = v;      // out[:,0,:] = x[:,0,:]
        xv_hold = xb[NBI];                                  // x[b][1][m]
    }
    __syncthreads();

    f32x4 c = {0.f, 0.f, 0.f, 0.f};
    int cur = 0;

    // ================= teacher phase: t = 0 .. T_INP =================
    for (int t = 0; t <= T_INP; ++t) {
        const int nxt = cur ^ 1;

        // prefetch x for t+2 (2-step window hides HBM miss)
        if (do_x && t + 2 <= T_INP) xv_pref = xb[(t + 2) * NBI];

        // ---- G phase ----
        f32x4 acc0 = binit[0], acc1 = binit[1], acc2 = binit[2], acc3 = binit[3];
        {
            half8 xf = x_s[cur][g][cb];
            acc0 = MFMA16(wxf[0], xf, acc0);
            acc1 = MFMA16(wxf[1], xf, acc1);
            acc2 = MFMA16(wxf[2], xf, acc2);
            acc3 = MFMA16(wxf[3], xf, acc3);
        }
        f32x4 pacc = {0.f, 0.f, 0.f, 0.f};
#pragma unroll
        for (int kk = 0; kk < 4; ++kk) {
            half8 hb = h_s[cur][4 * kk + g][cb];
            acc0 = MFMA16(wf[0][kk], hb, acc0);
            acc1 = MFMA16(wf[1][kk], hb, acc1);
            acc2 = MFMA16(wf[2][kk], hb, acc2);
            acc3 = MFMA16(wf[3][kk], hb, acc3);
            if (projw) pacc = MFMA16(wof[kk], hb, pacc);    // out[t] = W_out h^t
        }

        // ---- U phase: in-register, exp2-native (scales folded into W) ----
        half4 h4v;
#pragma unroll
        for (int r = 0; r < 4; ++r) {
            float ig = rcpf_(1.0f + exp2_(acc0[r]));
            float fg = rcpf_(1.0f + exp2_(acc1[r]));
            float eg = exp2_(acc2[r]);
            float gg = 1.0f - 2.0f * rcpf_(eg + 1.0f);
            float og = rcpf_(1.0f + exp2_(acc3[r]));
            float cn = fg * c[r] + ig * gg;
            c[r] = cn;
            float ec = exp2_(cn * 2.8853900817779268f);
            h4v[r] = (_Float16)(og * (1.0f - 2.0f * rcpf_(ec + 1.0f)));
        }
        {   // h rows 16w+4g+0..3, col cb
            _Float16* hp = (_Float16*)&h_s[nxt][2 * w + (g >> 1)][cb];
            *(half4*)(hp + 4 * (g & 1)) = h4v;
        }
        if (do_x && t + 1 <= T_INP) {
            ((_Float16*)&x_s[nxt][sm >> 3][sb])[sm & 7] = (_Float16)xv_hold;
            xv_hold = xv_pref;
        }
        if (projw && t >= 1) {
#pragma unroll
            for (int r = 0; r < 4; ++r)
                if (4 * g + r < NBI) pob[t * NBI + r] = pacc[r] + bo[r];
        }
        barrier_lds();
        cur = nxt;
    }

    // ---- switch to folded weights / auto bias (uniform, no barrier needed) ----
#pragma unroll
    for (int gate = 0; gate < 4; ++gate) {
        const int row = 128 * gate + 16 * w + cb;
#pragma unroll
        for (int kk = 0; kk < 4; ++kk)
            wf[gate][kk] = *(const half8*)(what16 + row * HH + 32 * kk + 8 * g);
#pragma unroll
        for (int r = 0; r < 4; ++r)
            binit[gate][r] = bafp[128 * gate + 16 * w + 4 * g + r];
    }

    // ================= auto phase: t = T_INP+1 .. TT-2 =================
    for (int t = T_INP + 1; t < TT - 1; ++t) {
        const int nxt = cur ^ 1;

        f32x4 acc0 = binit[0], acc1 = binit[1], acc2 = binit[2], acc3 = binit[3];
        f32x4 pacc = {0.f, 0.f, 0.f, 0.f};
#pragma unroll
        for (int kk = 0; kk < 4; ++kk) {
            half8 hb = h_s[cur][4 * kk + g][cb];
            acc0 = MFMA16(wf[0][kk], hb, acc0);
            acc1 = MFMA16(wf[1][kk], hb, acc1);
            acc2 = MFMA16(wf[2][kk], hb, acc2);
            acc3 = MFMA16(wf[3][kk], hb, acc3);
            if (projw) pacc = MFMA16(wof[kk], hb, pacc);
        }

        half4 h4v;
#pragma unroll
        for (int r = 0; r < 4; ++r) {
            float ig = rcpf_(1.0f + exp2_(acc0[r]));
            float fg = rcpf_(1.0f + exp2_(acc1[r]));
            float eg = exp2_(acc2[r]);
            float gg = 1.0f - 2.0f * rcpf_(eg + 1.0f);
            float og = rcpf_(1.0f + exp2_(acc3[r]));
            float cn = fg * c[r] + ig * gg;
            c[r] = cn;
            float ec = exp2_(cn * 2.8853900817779268f);
            h4v[r] = (_Float16)(og * (1.0f - 2.0f * rcpf_(ec + 1.0f)));
        }
        {
            _Float16* hp = (_Float16*)&h_s[nxt][2 * w + (g >> 1)][cb];
            *(half4*)(hp + 4 * (g & 1)) = h4v;
        }
        if (projw) {
#pragma unroll
            for (int r = 0; r < 4; ++r)
                if (4 * g + r < NBI) pob[t * NBI + r] = pacc[r] + bo[r];
        }
        barrier_lds();
        cur = nxt;
    }

    // ---- epilogue: out[127] = W_out h^127 + b_out ----
    if (projw) {
        f32x4 pacc = {0.f, 0.f, 0.f, 0.f};
#pragma unroll
        for (int kk = 0; kk < 4; ++kk) {
            half8 hb = h_s[cur][4 * kk + g][cb];
            pacc = MFMA16(wof[kk], hb, pacc);
        }
#pragma unroll
        for (int r = 0; r < 4; ++r)
            if (4 * g + r < NBI) pob[(TT - 1) * NBI + r] = pacc[r] + bo[r];
    }
}

extern "C" void kernel_launch(void* const* d_in, const int* in_sizes, int n_in,
                              void* d_out, int out_size, void* d_ws, size_t ws_size,
                              hipStream_t stream)
{
    const float* x     = (const float*)d_in[0];
    const float* W_ih  = (const float*)d_in[1];
    const float* W_hh  = (const float*)d_in[2];
    const float* b_ih  = (const float*)d_in[3];
    const float* b_hh  = (const float*)d_in[4];
    const float* W_out = (const float*)d_in[5];
    const float* b_out = (const float*)d_in[6];
    float* out = (float*)d_out;
    unsigned char* ws = (unsigned char*)d_ws;

    fold_kernel<<<512, HH, 0, stream>>>(W_ih, W_hh, b_ih, b_hh, W_out, b_out, ws);
    lstm_main<<<NBLK, 512, 0, stream>>>(x, b_out, ws, out);
}

// Round 3
// 179.022 us; speedup vs baseline: 2.1117x; 1.0413x over previous
//
#include <hip/hip_runtime.h>
#include <math.h>

#define BATCH 1024
#define TT    128
#define NBI   13
#define HH    128
#define T_INP 64
#define BB    16           // batch elements per block
#define NBLK  (BATCH/BB)   // 64 blocks

#define LOG2E 1.4426950408889634f
#define C2L   2.8853900817779268f   // 2*log2e  (c-state scale)
#define C4L   5.7707801635558537f   // 4*log2e

typedef _Float16 half8 __attribute__((ext_vector_type(8)));
typedef _Float16 half4 __attribute__((ext_vector_type(4)));
typedef float    f32x4 __attribute__((ext_vector_type(4)));

__device__ __forceinline__ unsigned short f16b(float v) {
    return __builtin_bit_cast(unsigned short, (_Float16)v);
}
__device__ __forceinline__ float rcpf_(float x) { return __builtin_amdgcn_rcpf(x); }

#if __has_builtin(__builtin_amdgcn_exp2f)
__device__ __forceinline__ float exp2_(float x) { return __builtin_amdgcn_exp2f(x); }
#else
__device__ __forceinline__ float exp2_(float x) { return __expf(x * 0.6931471805599453f); }
#endif

// light barrier: LDS visibility only — never drain vmcnt in the step loop
__device__ __forceinline__ void barrier_lds() {
    asm volatile("s_waitcnt lgkmcnt(0)" ::: "memory");
    __builtin_amdgcn_sched_barrier(0);
    __builtin_amdgcn_s_barrier();
    __builtin_amdgcn_sched_barrier(0);
}

// ---- ws layout (bytes) ----
// gate rows pre-scaled: i/f/o rows by -log2e, g rows by +2*log2e.
#define WS_WHH   0            // ushort[512*128] teacher W_hh (f16, scaled)
#define WS_WHAT  131072       // ushort[512*128] folded W^ (f16, scaled)
#define WS_WIHP  262144       // ushort[512*32]  W_ih padded 13->32 (f16, scaled)
#define WS_WOUT  294912       // ushort[16*128]  W_out padded 13->16 rows (f16)
#define WS_BT    299008       // float[512] teacher bias (scaled)
#define WS_BA    301056       // float[512] auto bias (scaled)

__global__ void fold_kernel(const float* __restrict__ W_ih,
                            const float* __restrict__ W_hh,
                            const float* __restrict__ b_ih,
                            const float* __restrict__ b_hh,
                            const float* __restrict__ W_out,
                            const float* __restrict__ b_out,
                            unsigned char* __restrict__ ws)
{
    const int j = blockIdx.x;   // gate row 0..511
    const int k = threadIdx.x;  // hidden col 0..127
    unsigned short* whh16  = (unsigned short*)(ws + WS_WHH);
    unsigned short* what16 = (unsigned short*)(ws + WS_WHAT);
    unsigned short* wihp16 = (unsigned short*)(ws + WS_WIHP);
    unsigned short* wout16 = (unsigned short*)(ws + WS_WOUT);
    float* bias_t = (float*)(ws + WS_BT);
    float* bias_a = (float*)(ws + WS_BA);

    const int gate = j >> 7;
    const float sc = (gate == 2) ? (2.0f * LOG2E) : (-LOG2E);

    float whh = W_hh[j * HH + k];
    float acc = whh;
#pragma unroll
    for (int m = 0; m < NBI; ++m)
        acc += W_ih[j * NBI + m] * W_out[m * HH + k];
    whh16[j * HH + k]  = f16b(sc * whh);
    what16[j * HH + k] = f16b(sc * acc);

    if (k < 32) wihp16[j * 32 + k] = (k < NBI) ? f16b(sc * W_ih[j * NBI + k]) : (unsigned short)0;
    if (k == 0) {
        float bt = b_ih[j] + b_hh[j];
        bias_t[j] = sc * bt;
        float ba = bt;
#pragma unroll
        for (int m = 0; m < NBI; ++m) ba += W_ih[j * NBI + m] * b_out[m];
        bias_a[j] = sc * ba;
    }
    if (j < 16) wout16[j * HH + k] = (j < NBI) ? f16b(W_out[j * HH + k]) : (unsigned short)0;
}

#define MFMA16(A, B, C) __builtin_amdgcn_mfma_f32_16x16x32_f16((A), (B), (C), 0, 0, 0)

__global__ __launch_bounds__(512, 2)
void lstm_main(const float* __restrict__ x,
               const float* __restrict__ b_out,
               const unsigned char* __restrict__ ws,
               float* __restrict__ out)
{
    const int j  = threadIdx.x;
    const int w  = j >> 6;        // wave 0..7 : owns h-slice [16w,16w+16)
    const int l  = j & 63;
    const int g  = l >> 4;        // lane group 0..3
    const int cb = l & 15;        // B col (batch) / A row within tile
    const int bbase = blockIdx.x * BB;

    const unsigned short* whh16  = (const unsigned short*)(ws + WS_WHH);
    const unsigned short* what16 = (const unsigned short*)(ws + WS_WHAT);
    const unsigned short* wihp16 = (const unsigned short*)(ws + WS_WIHP);
    const unsigned short* wout16 = (const unsigned short*)(ws + WS_WOUT);
    const float* btfp = (const float*)(ws + WS_BT);
    const float* bafp = (const float*)(ws + WS_BA);

    __shared__ half8 h_s[2][16][16];       // h state, k = 8*kc + i
    __shared__ half8 x_s[2][4][16];        // x_t padded to K=32
    __shared__ float o_s[2][4][16][16];    // out rows [buf][t&3][batch][m(pad16)]
    float* o_sf = &o_s[0][0][0][0];

    // ---- register-resident A fragments ----
    half8 wf[4][4];
    half8 wxf[4];
    half8 wof[4];
    f32x4 binit[4];
#pragma unroll
    for (int gate = 0; gate < 4; ++gate) {
        const int row = 128 * gate + 16 * w + cb;
#pragma unroll
        for (int kk = 0; kk < 4; ++kk)
            wf[gate][kk] = *(const half8*)(whh16 + row * HH + 32 * kk + 8 * g);
        wxf[gate] = *(const half8*)(wihp16 + row * 32 + 8 * g);
#pragma unroll
        for (int r = 0; r < 4; ++r)
            binit[gate][r] = btfp[128 * gate + 16 * w + 4 * g + r];
    }
    const bool projw = (w == 7);
#pragma unroll
    for (int kk = 0; kk < 4; ++kk)
        wof[kk] = *(const half8*)(wout16 + cb * HH + 32 * kk + 8 * g);

    f32x4 bo4;
#pragma unroll
    for (int r = 0; r < 4; ++r) {
        const int m = 4 * g + r;
        bo4[r] = (m < NBI) ? b_out[m] : 0.0f;
    }
    const f32x4 z4 = {0.f, 0.f, 0.f, 0.f};

    // ---- flush role: 208 threads (waves 0-3) write 4 out-rows every 4 steps ----
    const bool fl_act = (j < 208);
    int floff0 = 0, floff1 = 0, floff2 = 0, floff3 = 0;
    float* fgout = out;
    if (fl_act) {
        const int fb = j / 13, fq = j - 13 * fb;
        fgout = out + (size_t)(bbase + fb) * TT * NBI + 4 * fq;
#pragma unroll
        for (int i = 0; i < 4; ++i) {
            int s = 4 * fq + i;
            int tr = (s >= 39) ? 3 : (s >= 26) ? 2 : (s >= 13) ? 1 : 0;
            int m  = s - 13 * tr;
            int off = (tr * 16 + fb) * 16 + m;
            if (i == 0) floff0 = off; else if (i == 1) floff1 = off;
            else if (i == 2) floff2 = off; else floff3 = off;
        }
    }
#define FLUSH(FBUF, T0) do { if (fl_act) {                      \
        float4 fv;                                              \
        fv.x = o_sf[(FBUF) * 1024 + floff0];                    \
        fv.y = o_sf[(FBUF) * 1024 + floff1];                    \
        fv.z = o_sf[(FBUF) * 1024 + floff2];                    \
        fv.w = o_sf[(FBUF) * 1024 + floff3];                    \
        *(float4*)(fgout + (T0) * NBI) = fv; } } while (0)

    // ---- x staging role: 112 threads on waves 4-5, pairs of m ----
    const int  pidx = j - 256;
    const bool pair = (pidx >= 0) && (pidx < 112);
    const float* xp0 = x;
    unsigned x_woff = 0;
    int psix = 0;
    float xa_h = 0.f, xb_h = 0.f, xa_p = 0.f, xb_p = 0.f;

    // ---- init LDS ----
    if (j < 256) h_s[0][j >> 4][j & 15] = (half8)(_Float16)0.0f;    // h^0 = 0
    if (j < 128) ((half8*)x_s)[j] = (half8)(_Float16)0.0f;          // zero pads (both bufs)
    if (pair) {
        const int sb = pidx / 7, p = pidx - 7 * sb;
        const int m0 = (p < 6) ? 2 * p : 12;
        psix = (p == 6);
        xp0 = x + (size_t)(bbase + sb) * TT * NBI + m0;
        x_woff = (unsigned)((((m0 >> 3) * 16 + sb) * 16 + (m0 & 7) * 2));
        float v0 = xp0[0];
        float v1 = psix ? 0.0f : xp0[1];
        unsigned pk = (unsigned)f16b(v0) | ((unsigned)f16b(v1) << 16);
        *(unsigned*)((char*)&x_s[0][0][0] + x_woff) = pk;
        o_s[0][0][sb][m0] = v0;                      // out row 0 = x row 0
        if (!psix) o_s[0][0][sb][m0 + 1] = v1;
        xa_h = xp0[NBI];                             // x[b][1][...]
        xb_h = psix ? 0.0f : xp0[NBI + 1];
    }
    __syncthreads();

    f32x4 c = {0.f, 0.f, 0.f, 0.f};   // c state pre-scaled by 2*log2e
    int cur = 0;

    // ================= teacher phase: t = 0 .. T_INP =================
    for (int t = 0; t <= T_INP; ++t) {
        const int nxt = cur ^ 1;

        if ((t & 3) == 0 && t) FLUSH(((t >> 2) - 1) & 1, t - 4);

        if (pair && t + 2 <= T_INP) {
            xa_p = xp0[(t + 2) * NBI];
            xb_p = psix ? 0.0f : xp0[(t + 2) * NBI + 1];
        }

        // ---- G phase: hoisted LDS reads, bias as MFMA C-in ----
        half8 xf  = x_s[cur][g][cb];
        half8 hb0 = h_s[cur][g][cb];
        half8 hb1 = h_s[cur][4 + g][cb];
        half8 hb2 = h_s[cur][8 + g][cb];
        half8 hb3 = h_s[cur][12 + g][cb];

        f32x4 acc0 = MFMA16(wxf[0], xf, binit[0]);
        f32x4 acc1 = MFMA16(wxf[1], xf, binit[1]);
        f32x4 acc2 = MFMA16(wxf[2], xf, binit[2]);
        f32x4 acc3 = MFMA16(wxf[3], xf, binit[3]);
        acc0 = MFMA16(wf[0][0], hb0, acc0); acc1 = MFMA16(wf[1][0], hb0, acc1);
        acc2 = MFMA16(wf[2][0], hb0, acc2); acc3 = MFMA16(wf[3][0], hb0, acc3);
        acc0 = MFMA16(wf[0][1], hb1, acc0); acc1 = MFMA16(wf[1][1], hb1, acc1);
        acc2 = MFMA16(wf[2][1], hb1, acc2); acc3 = MFMA16(wf[3][1], hb1, acc3);
        acc0 = MFMA16(wf[0][2], hb2, acc0); acc1 = MFMA16(wf[1][2], hb2, acc1);
        acc2 = MFMA16(wf[2][2], hb2, acc2); acc3 = MFMA16(wf[3][2], hb2, acc3);
        acc0 = MFMA16(wf[0][3], hb3, acc0); acc1 = MFMA16(wf[1][3], hb3, acc1);
        acc2 = MFMA16(wf[2][3], hb3, acc2); acc3 = MFMA16(wf[3][3], hb3, acc3);

        f32x4 pacc = z4;
        if (projw) {
            pacc = MFMA16(wof[0], hb0, z4);
            pacc = MFMA16(wof[1], hb1, pacc);
            pacc = MFMA16(wof[2], hb2, pacc);
            pacc = MFMA16(wof[3], hb3, pacc);
        }

        // ---- U phase (c pre-scaled by 2*log2e) ----
        half4 h4v;
#pragma unroll
        for (int r = 0; r < 4; ++r) {
            float ig = rcpf_(1.0f + exp2_(acc0[r]));
            float fg = rcpf_(1.0f + exp2_(acc1[r]));
            float rg = rcpf_(exp2_(acc2[r]) + 1.0f);
            float gp = C2L - C4L * rg;               // 2log2e * tanh(g)
            float og = rcpf_(1.0f + exp2_(acc3[r]));
            float cn = fg * c[r] + ig * gp;
            c[r] = cn;
            float ec = exp2_(cn);
            h4v[r] = (_Float16)(og * (1.0f - 2.0f * rcpf_(ec + 1.0f)));
        }
        {
            _Float16* hp = (_Float16*)&h_s[nxt][2 * w + (g >> 1)][cb];
            *(half4*)(hp + 4 * (g & 1)) = h4v;
        }
        if (pair && t + 1 <= T_INP) {
            unsigned pk = (unsigned)f16b(xa_h) | ((unsigned)f16b(xb_h) << 16);
            *(unsigned*)((char*)&x_s[nxt][0][0] + x_woff) = pk;
            xa_h = xa_p; xb_h = xb_p;
        }
        if (projw && t >= 1)
            *(f32x4*)&o_s[(t >> 2) & 1][t & 3][cb][4 * g] = pacc + bo4;

        barrier_lds();
        cur = nxt;
    }

    // ---- switch to folded weights / auto bias ----
#pragma unroll
    for (int gate = 0; gate < 4; ++gate) {
        const int row = 128 * gate + 16 * w + cb;
#pragma unroll
        for (int kk = 0; kk < 4; ++kk)
            wf[gate][kk] = *(const half8*)(what16 + row * HH + 32 * kk + 8 * g);
#pragma unroll
        for (int r = 0; r < 4; ++r)
            binit[gate][r] = bafp[128 * gate + 16 * w + 4 * g + r];
    }

    // ================= auto phase: t = T_INP+1 .. TT-2 =================
    for (int t = T_INP + 1; t < TT - 1; ++t) {
        const int nxt = cur ^ 1;

        if ((t & 3) == 0) FLUSH(((t >> 2) - 1) & 1, t - 4);

        half8 hb0 = h_s[cur][g][cb];
        half8 hb1 = h_s[cur][4 + g][cb];
        half8 hb2 = h_s[cur][8 + g][cb];
        half8 hb3 = h_s[cur][12 + g][cb];

        f32x4 acc0 = MFMA16(wf[0][0], hb0, binit[0]);
        f32x4 acc1 = MFMA16(wf[1][0], hb0, binit[1]);
        f32x4 acc2 = MFMA16(wf[2][0], hb0, binit[2]);
        f32x4 acc3 = MFMA16(wf[3][0], hb0, binit[3]);
        acc0 = MFMA16(wf[0][1], hb1, acc0); acc1 = MFMA16(wf[1][1], hb1, acc1);
        acc2 = MFMA16(wf[2][1], hb1, acc2); acc3 = MFMA16(wf[3][1], hb1, acc3);
        acc0 = MFMA16(wf[0][2], hb2, acc0); acc1 = MFMA16(wf[1][2], hb2, acc1);
        acc2 = MFMA16(wf[2][2], hb2, acc2); acc3 = MFMA16(wf[3][2], hb2, acc3);
        acc0 = MFMA16(wf[0][3], hb3, acc0); acc1 = MFMA16(wf[1][3], hb3, acc1);
        acc2 = MFMA16(wf[2][3], hb3, acc2); acc3 = MFMA16(wf[3][3], hb3, acc3);

        f32x4 pacc = z4;
        if (projw) {
            pacc = MFMA16(wof[0], hb0, z4);
            pacc = MFMA16(wof[1], hb1, pacc);
            pacc = MFMA16(wof[2], hb2, pacc);
            pacc = MFMA16(wof[3], hb3, pacc);
        }

        half4 h4v;
#pragma unroll
        for (int r = 0; r < 4; ++r) {
            float ig = rcpf_(1.0f + exp2_(acc0[r]));
            float fg = rcpf_(1.0f + exp2_(acc1[r]));
            float rg = rcpf_(exp2_(acc2[r]) + 1.0f);
            float gp = C2L - C4L * rg;
            float og = rcpf_(1.0f + exp2_(acc3[r]));
            float cn = fg * c[r] + ig * gp;
            c[r] = cn;
            float ec = exp2_(cn);
            h4v[r] = (_Float16)(og * (1.0f - 2.0f * rcpf_(ec + 1.0f)));
        }
        {
            _Float16* hp = (_Float16*)&h_s[nxt][2 * w + (g >> 1)][cb];
            *(half4*)(hp + 4 * (g & 1)) = h4v;
        }
        if (projw)
            *(f32x4*)&o_s[(t >> 2) & 1][t & 3][cb][4 * g] = pacc + bo4;

        barrier_lds();
        cur = nxt;
    }

    // ---- epilogue: out row 127 = W_out h^127 + b_out ----
    if (projw) {
        half8 hb0 = h_s[cur][g][cb];
        half8 hb1 = h_s[cur][4 + g][cb];
        half8 hb2 = h_s[cur][8 + g][cb];
        half8 hb3 = h_s[cur][12 + g][cb];
        f32x4 pacc = MFMA16(wof[0], hb0, z4);
        pacc = MFMA16(wof[1], hb1, pacc);
        pacc = MFMA16(wof[2], hb2, pacc);
        pacc = MFMA16(wof[3], hb3, pacc);
        *(f32x4*)&o_s[1][3][cb][4 * g] = pacc + bo4;   // t=127: buf (127>>2)&1=1, trel 3
    }
    barrier_lds();
    FLUSH(1, 124);                                     // rows 124..127
#undef FLUSH
}

extern "C" void kernel_launch(void* const* d_in, const int* in_sizes, int n_in,
                              void* d_out, int out_size, void* d_ws, size_t ws_size,
                              hipStream_t stream)
{
    const float* x     = (const float*)d_in[0];
    const float* W_ih  = (const float*)d_in[1];
    const float* W_hh  = (const float*)d_in[2];
    const float* b_ih  = (const float*)d_in[3];
    const float* b_hh  = (const float*)d_in[4];
    const float* W_out = (const float*)d_in[5];
    const float* b_out = (const float*)d_in[6];
    float* out = (float*)d_out;
    unsigned char* ws = (unsigned char*)d_ws;

    fold_kernel<<<512, HH, 0, stream>>>(W_ih, W_hh, b_ih, b_hh, W_out, b_out, ws);
    lstm_main<<<NBLK, 512, 0, stream>>>(x, b_out, ws, out);
}